// Round 6
// baseline (404.679 us; speedup 1.0000x reference)
//
#include <hip/hip_runtime.h>
#include <cstdint>
#include <cstddef>

#define B_ 16
#define S_ 64
#define T_ 4096
#define C_ 512
#define H_ 8

// ws layout (float offsets):
#define WS_QKT     0          // [512][8]
#define WS_QB      4096       // [8]
#define WS_QH      4104       // [512]
#define WS_LG      4616       // [1024][8] softmax denominators (unnormalized)
#define WS_CNT     12808      // [16] int
#define WS_CSEG    12824      // [16][128] int
#define WS_CIDX    14872      // [16][128] int
#define WS_CMUL    16920      // [16][128] int
#define WS_ATT     18968      // [B][H][T] (524288)
#define WS_EHT     543256     // [16][4096][512] transposed eh (33554432)
#define WS_WSUM    34097688   // [1024][8][512] (4194304)
#define WS_ATTNOUT 38291992   // [1024][512] (524288)
// end 38816280 floats ~= 148 MB

// P1: qh[r] = (Wq@x + bq)[r] / 8.  grid 16, block 256.
__global__ void k_prep1(const float* __restrict__ x, const float* __restrict__ Wq,
                        const float* __restrict__ bq, float* __restrict__ qh_g) {
  __shared__ float xs[C_];
  __shared__ float red[256];
  int tid = threadIdx.x;
  xs[tid] = x[tid];
  xs[tid + 256] = x[tid + 256];
  __syncthreads();
  int r0 = blockIdx.x * 32;
  int rl = tid >> 3, sub = tid & 7;
  int r = r0 + rl;
  const float* wr = Wq + (size_t)r * C_ + sub * 64;
  const float* xp = xs + sub * 64;
  float s = 0.f;
#pragma unroll
  for (int i = 0; i < 64; i += 4) {
    float4 w = *(const float4*)(wr + i);
    s += w.x * xp[i] + w.y * xp[i + 1] + w.z * xp[i + 2] + w.w * xp[i + 3];
  }
  red[tid] = s;
  __syncthreads();
  if (sub == 0) {
    float tot = bq[r];
#pragma unroll
    for (int i = 0; i < 8; ++i) tot += red[rl * 8 + i];
    qh_g[r] = tot * 0.125f;
  }
}

// P2: qkT[c][h] = sum_d qh[h*64+d]*Wk[h*64+d][c]; qb[h] = sum_d qh*bk.
__global__ void k_prep2(const float* __restrict__ qh_g,
                        const float* __restrict__ Wk,
                        const float* __restrict__ bk, float* __restrict__ qkT,
                        float* __restrict__ qb) {
  __shared__ float qhs[64];
  int tid = threadIdx.x;
  int h = blockIdx.x;
  if (tid < 64) qhs[tid] = qh_g[h * 64 + tid];
  __syncthreads();
  int c0 = tid, c1 = tid + 256;
  float s0 = 0.f, s1 = 0.f;
#pragma unroll 8
  for (int d = 0; d < 64; ++d) {
    const float* row = Wk + (size_t)(h * 64 + d) * C_;
    float q = qhs[d];
    s0 += q * row[c0];
    s1 += q * row[c1];
  }
  qkT[c0 * 8 + h] = s0;
  qkT[c1 * 8 + h] = s1;
  if (tid < 64) {
    float w = qhs[tid] * bk[h * 64 + tid];
#pragma unroll
    for (int off = 32; off > 0; off >>= 1) w += __shfl_down(w, off, 64);
    if (tid == 0) qb[h] = w;
  }
}

// K2: fused att + transpose.
// att[b][h][t] = qb[h] + sum_c qkT[c][h]*eh[b][c][t];  ehT[b][t][c] = eh[b][c][t]
// grid (64, 16), block 256: 64 t per block; 4 sequential c-groups of 128.
__global__ __launch_bounds__(256, 2) void k_atx(
    const float* __restrict__ eh, const float* __restrict__ qkT,
    const float* __restrict__ qb, float* __restrict__ att,
    float* __restrict__ ehT) {
  __shared__ float qks[C_ * 8];        // 16 KB  [c][h]
  __shared__ float tile[64 * 130];     // 33.3 KB [t][c-in-group], stride 130
  __shared__ float part[4 * 8 * 64];   // 8 KB [w][h][t]
  int tid = threadIdx.x;
  int tl = tid & 63, w = tid >> 6;
  int b = blockIdx.y;
  int t0 = blockIdx.x * 64;
#pragma unroll
  for (int i = 0; i < 16; ++i) qks[tid + i * 256] = qkT[tid + i * 256];
  __syncthreads();
  float acc[8];
#pragma unroll
  for (int h = 0; h < 8; ++h) acc[h] = 0.f;
  for (int g = 0; g < 4; ++g) {
    const float* ehp = eh + ((size_t)b * C_ + g * 128 + w * 32) * T_ + t0 + tl;
    const float* qp = qks + (g * 128 + w * 32) * 8;
    float* tp = tile + tl * 130 + w * 32;
#pragma unroll 8
    for (int j = 0; j < 32; ++j) {
      float e = ehp[(size_t)j * T_];           // coalesced along t
      const float4 q0 = *(const float4*)&qp[j * 8];
      const float4 q1 = *(const float4*)&qp[j * 8 + 4];
      acc[0] += q0.x * e; acc[1] += q0.y * e; acc[2] += q0.z * e; acc[3] += q0.w * e;
      acc[4] += q1.x * e; acc[5] += q1.y * e; acc[6] += q1.z * e; acc[7] += q1.w * e;
      tp[j] = e;
    }
    __syncthreads();
    // transpose store: wave w covers t_loc = w*16..w*16+15; lanes along c.
    float* eo = ehT + ((size_t)b * T_ + t0 + w * 16) * C_ + g * 128 + tl * 2;
#pragma unroll
    for (int r = 0; r < 16; ++r) {
      float2 v = *(const float2*)&tile[(w * 16 + r) * 130 + tl * 2];
      *(float2*)(eo + (size_t)r * C_) = v;     // coalesced along c
    }
    __syncthreads();
  }
#pragma unroll
  for (int h = 0; h < 8; ++h) part[(w * 8 + h) * 64 + tl] = acc[h];
  __syncthreads();
#pragma unroll
  for (int i = 0; i < 2; ++i) {
    int idx = tid + i * 256;
    int h = idx >> 6, tt = idx & 63;
    float v = part[(0 * 8 + h) * 64 + tt] + part[(1 * 8 + h) * 64 + tt] +
              part[(2 * 8 + h) * 64 + tt] + part[(3 * 8 + h) * 64 + tt] + qb[h];
    att[((size_t)b * H_ + h) * T_ + t0 + tt] = v;
  }
}

// K3: chunk map, chunks of 256 t. grid 16, block 64.
__global__ void k_map(const int* __restrict__ starts,
                      const int* __restrict__ ends, int* __restrict__ cnt,
                      int* __restrict__ cseg, int* __restrict__ cidx,
                      int* __restrict__ cmul) {
  int b = blockIdx.x;
  int s = threadIdx.x;
  int st = starts[b * 64 + s], en = ends[b * 64 + s];
  int nch = (en - st + 255) >> 8;
  int x = nch;
#pragma unroll
  for (int off = 1; off < 64; off <<= 1) {
    int y = __shfl_up(x, off, 64);
    if (s >= off) x += y;
  }
  int pre = x - nch;
  for (int k = 0; k < nch; ++k) {
    cseg[b * 128 + pre + k] = s;
    cidx[b * 128 + pre + k] = k;
    cmul[b * 128 + pre + k] = (nch > 1) ? 1 : 0;
  }
  if (s == 63) cnt[b] = x;
}

// K4: per 256-t chunk: e = exp(att), l_g[n][h] += sum(e) (atomic),
// wsum[n][h][c] (+)= sum_t e[h][t]*ehT[b][t][c].
// Lanes own 2 consecutive c (float2) -> fully coalesced ehT reads.
__global__ __launch_bounds__(256, 4) void k_wsum(
    const float* __restrict__ ehT, const float* __restrict__ att,
    const int* __restrict__ starts, const int* __restrict__ ends,
    const int* __restrict__ cnt, const int* __restrict__ cseg,
    const int* __restrict__ cidx, const int* __restrict__ cmul,
    float* __restrict__ wsum, float* __restrict__ l_g) {
  __shared__ float pl[8 * 260];  // [h][t-t_lo], stride 260 (16B-aligned rows)
  int b = blockIdx.y;
  int i = blockIdx.x;
  if (i >= cnt[b]) return;
  int tid = threadIdx.x;
  int s = cseg[b * 128 + i];
  int k = cidx[b * 128 + i];
  int mul = cmul[b * 128 + i];
  int n = b * 64 + s;
  int st = starts[n], en = ends[n];
  int t_lo = st + k * 256;
  int t_hi = t_lo + 256 < en ? t_lo + 256 : en;
  int span = t_hi - t_lo;

  // stage e = exp(att) (unnormalized softmax; att ~ N(0,1) so exp is safe)
#pragma unroll
  for (int r = 0; r < 8; ++r) {
    int idx = tid + r * 256;
    int h = idx >> 8, tt = idx & 255;
    float pv = 0.f;
    if (tt < span)
      pv = __expf(att[((size_t)b * H_ + h) * T_ + t_lo + tt]);
    pl[h * 260 + tt] = pv;
  }
  __syncthreads();

  // denominator partial -> atomicAdd
  if (tid < 64) {
    int h = tid >> 3, k8 = tid & 7;
    float ls = 0.f;
#pragma unroll
    for (int q = 0; q < 32; ++q) ls += pl[h * 260 + k8 * 32 + q];
    ls += __shfl_down(ls, 4, 8);
    ls += __shfl_down(ls, 2, 8);
    ls += __shfl_down(ls, 1, 8);
    if (k8 == 0) atomicAdd(&l_g[n * 8 + h], ls);
  }

  float2 acc[8];
#pragma unroll
  for (int h = 0; h < 8; ++h) { acc[h].x = 0.f; acc[h].y = 0.f; }
  const float* ep = ehT + ((size_t)b * T_ + t_lo) * C_ + tid * 2;
  int j = 0;
  for (; j + 4 <= span; j += 4) {
    float2 e0 = *(const float2*)(ep + (size_t)(j + 0) * C_);
    float2 e1 = *(const float2*)(ep + (size_t)(j + 1) * C_);
    float2 e2 = *(const float2*)(ep + (size_t)(j + 2) * C_);
    float2 e3 = *(const float2*)(ep + (size_t)(j + 3) * C_);
#pragma unroll
    for (int h = 0; h < 8; ++h) {
      const float4 p = *(const float4*)&pl[h * 260 + j];  // broadcast b128
      acc[h].x += p.x * e0.x + p.y * e1.x + p.z * e2.x + p.w * e3.x;
      acc[h].y += p.x * e0.y + p.y * e1.y + p.z * e2.y + p.w * e3.y;
    }
  }
  for (; j < span; ++j) {
    float2 e = *(const float2*)(ep + (size_t)j * C_);
#pragma unroll
    for (int h = 0; h < 8; ++h) {
      float p = pl[h * 260 + j];
      acc[h].x += p * e.x;
      acc[h].y += p * e.y;
    }
  }
  float* wp = wsum + (size_t)n * (H_ * C_) + tid * 2;
  if (!mul) {
#pragma unroll
    for (int h = 0; h < 8; ++h) *(float2*)&wp[h * C_] = acc[h];
  } else {
#pragma unroll
    for (int h = 0; h < 8; ++h) {
      atomicAdd(&wp[h * C_], acc[h].x);
      atomicAdd(&wp[h * C_ + 1], acc[h].y);
    }
  }
}

// K5/K6: C[n][y*64+j] = (sum_k A[n*aRow + y*aColPerY + k]*Bm[(y*64+j)*512+k])
//        * (l_g ? 1/l_g[n*8+y] : 1) + bias[y*64+j].  32x64 tile.
__global__ __launch_bounds__(256, 4) void k_gemm(
    const float* __restrict__ A, long aRow, long aColPerY,
    const float* __restrict__ Bm, const float* __restrict__ bias,
    const float* __restrict__ l_g, float* __restrict__ Cc) {
  __shared__ float As[32 * 36];
  __shared__ float Bs[64 * 36];
  int tid = threadIdx.x;
  int n0 = blockIdx.x * 32;
  int y = blockIdx.y;
  const float* Abase = A + (size_t)n0 * aRow + (size_t)y * aColPerY;
  const float* Bbase = Bm + (size_t)(y * 64) * C_;
  int tx = tid & 15, ty = tid >> 4;
  float acc[2][4];
#pragma unroll
  for (int a = 0; a < 2; ++a)
#pragma unroll
    for (int bb = 0; bb < 4; ++bb) acc[a][bb] = 0.f;
  for (int k0 = 0; k0 < 512; k0 += 32) {
#pragma unroll
    for (int i = 0; i < 4; ++i) {
      int idx = tid + i * 256;
      int r = idx >> 5, cc = idx & 31;
      As[r * 36 + cc] = Abase[(size_t)r * aRow + k0 + cc];
    }
#pragma unroll
    for (int i = 0; i < 8; ++i) {
      int idx = tid + i * 256;
      int r = idx >> 5, cc = idx & 31;
      Bs[r * 36 + cc] = Bbase[(size_t)r * C_ + k0 + cc];
    }
    __syncthreads();
#pragma unroll
    for (int k = 0; k < 32; k += 4) {
      const float4 a0 = *(const float4*)&As[(ty * 2 + 0) * 36 + k];
      const float4 a1 = *(const float4*)&As[(ty * 2 + 1) * 36 + k];
#pragma unroll
      for (int bb = 0; bb < 4; ++bb) {
        const float4 bv = *(const float4*)&Bs[(tx * 4 + bb) * 36 + k];
        acc[0][bb] += a0.x * bv.x + a0.y * bv.y + a0.z * bv.z + a0.w * bv.w;
        acc[1][bb] += a1.x * bv.x + a1.y * bv.y + a1.z * bv.z + a1.w * bv.w;
      }
    }
    __syncthreads();
  }
#pragma unroll
  for (int a = 0; a < 2; ++a) {
    int nn = n0 + ty * 2 + a;
    float sc = l_g ? (1.0f / l_g[nn * 8 + y]) : 1.0f;
    float4 o;
    o.x = acc[a][0] * sc + bias[y * 64 + tx * 4 + 0];
    o.y = acc[a][1] * sc + bias[y * 64 + tx * 4 + 1];
    o.z = acc[a][2] * sc + bias[y * 64 + tx * 4 + 2];
    o.w = acc[a][3] * sc + bias[y * 64 + tx * 4 + 3];
    *(float4*)&Cc[(size_t)nn * C_ + y * 64 + tx * 4] = o;
  }
}

extern "C" void kernel_launch(void* const* d_in, const int* in_sizes, int n_in,
                              void* d_out, int out_size, void* d_ws,
                              size_t ws_size, hipStream_t stream) {
  const float* x = (const float*)d_in[0];
  const float* eh = (const float*)d_in[1];
  const int* shot_starts = (const int*)d_in[2];
  const int* shot_ends = (const int*)d_in[3];
  const float* Wq = (const float*)d_in[4];
  const float* bq = (const float*)d_in[5];
  const float* Wk = (const float*)d_in[6];
  const float* bk = (const float*)d_in[7];
  const float* Wv = (const float*)d_in[8];
  const float* bv = (const float*)d_in[9];
  const float* Wp = (const float*)d_in[10];
  const float* bp = (const float*)d_in[11];
  float* out = (float*)d_out;

  float* ws = (float*)d_ws;
  float* qkT = ws + WS_QKT;
  float* qb = ws + WS_QB;
  float* qh = ws + WS_QH;
  float* l_g = ws + WS_LG;
  int* cnt = (int*)(ws + WS_CNT);
  int* cseg = (int*)(ws + WS_CSEG);
  int* cidx = (int*)(ws + WS_CIDX);
  int* cmul = (int*)(ws + WS_CMUL);
  float* att = ws + WS_ATT;
  float* ehT = ws + WS_EHT;
  float* wsum = ws + WS_WSUM;
  float* attnout = ws + WS_ATTNOUT;

  hipMemsetAsync(wsum, 0, (size_t)1024 * H_ * C_ * sizeof(float), stream);
  hipMemsetAsync(l_g, 0, (size_t)1024 * H_ * sizeof(float), stream);
  k_prep1<<<16, 256, 0, stream>>>(x, Wq, bq, qh);
  k_prep2<<<8, 256, 0, stream>>>(qh, Wk, bk, qkT, qb);
  k_atx<<<dim3(T_ / 64, B_), 256, 0, stream>>>(eh, qkT, qb, att, ehT);
  k_map<<<B_, 64, 0, stream>>>(shot_starts, shot_ends, cnt, cseg, cidx, cmul);
  k_wsum<<<dim3(128, B_), 256, 0, stream>>>(ehT, att, shot_starts, shot_ends,
                                            cnt, cseg, cidx, cmul, wsum, l_g);
  k_gemm<<<dim3(32, 8), 256, 0, stream>>>(wsum, (long)(H_ * C_), (long)C_, Wv,
                                          bv, l_g, attnout);
  k_gemm<<<dim3(32, 8), 256, 0, stream>>>(attnout, (long)C_, 0L, Wp, bp,
                                          nullptr, out);
}